// Round 2
// baseline (728.812 us; speedup 1.0000x reference)
//
#include <hip/hip_runtime.h>
#include <hip/hip_bf16.h>

typedef __hip_bfloat16 bf16;
typedef __attribute__((ext_vector_type(8))) short bf16x8;   // 8 bf16 = 4 VGPRs
typedef __attribute__((ext_vector_type(4))) float f32x4;
typedef __attribute__((ext_vector_type(4))) int int4v;

#define AS1 __attribute__((address_space(1)))
#define AS3 __attribute__((address_space(3)))

#define MDIM 8192   // B*S
#define NDIM 4096   // D_OUT
#define KDIM 4096   // D_IN
#define SCALING 2.0f

// 1 => inputs are fp32 (reference dtype), 0 => harness converted to bf16
__device__ int g_isf32;

static __device__ __forceinline__ float tofl(bf16 v)  { return __bfloat162float(v); }
static __device__ __forceinline__ float tofl(float v) { return v; }

// load 8 consecutive elements as float[8], vectorized
static __device__ __forceinline__ void load8(const bf16* p, float* o) {
    bf16x8 v = *(const bf16x8*)p;
    const bf16* b = (const bf16*)&v;
#pragma unroll
    for (int e = 0; e < 8; ++e) o[e] = __bfloat162float(b[e]);
}
static __device__ __forceinline__ void load8(const float* p, float* o) {
    f32x4 a = *(const f32x4*)p;
    f32x4 c = *(const f32x4*)(p + 4);
#pragma unroll
    for (int e = 0; e < 4; ++e) { o[e] = a[e]; o[e + 4] = c[e]; }
}

// ---------------------------------------------------------------------------
// Detect input dtype from raw bits of x. fp32 N(0,1) data: low 16-bit halves
// are uniform random -> ~64 words with bf16-exp==0xFF among 16384.
// bf16 N(0,1) data: every word is a finite sample -> zero such words.
// ---------------------------------------------------------------------------
__global__ __launch_bounds__(256) void detect_dtype(const unsigned short* xw) {
    __shared__ int cnt;
    if (threadIdx.x == 0) cnt = 0;
    __syncthreads();
    int local = 0;
    for (int i = threadIdx.x; i < 16384; i += 256) {
        unsigned v = xw[i];
        if (((v >> 7) & 0xFFu) == 0xFFu) local++;
    }
    if (local) atomicAdd(&cnt, local);
    __syncthreads();
    if (threadIdx.x == 0) g_isf32 = (cnt > 0) ? 1 : 0;
}

// ---------------------------------------------------------------------------
// Fold: Weff[o][d] = W + SCALING*(lora_B@lora_A) + mask?delta : 0  -> bf16
// ---------------------------------------------------------------------------
template <typename TIN>
__global__ __launch_bounds__(256) void fold_weff(
    const TIN* __restrict__ W, const TIN* __restrict__ lA,
    const TIN* __restrict__ lB, const TIN* __restrict__ delta,
    const int* __restrict__ mask, bf16* __restrict__ Weff, int want)
{
    if (g_isf32 != want) return;
    int idx = blockIdx.x * 256 + threadIdx.x;   // 2,097,152 total
    int o   = idx >> 9;                          // 512 threads per row of 4096
    int d0  = (idx & 511) << 3;
    size_t base = (size_t)o * KDIM + d0;

    float Bo[16];
#pragma unroll
    for (int r = 0; r < 16; ++r) Bo[r] = tofl(lB[o * 16 + r]);

    float wv[8], dv[8];
    load8(W + base, wv);
    load8(delta + base, dv);

    int mk[8];
    *(int4v*)(mk)     = *(const int4v*)(mask + base);
    *(int4v*)(mk + 4) = *(const int4v*)(mask + base + 4);

    float lor[8] = {0.f, 0.f, 0.f, 0.f, 0.f, 0.f, 0.f, 0.f};
#pragma unroll
    for (int r = 0; r < 16; ++r) {
        float av[8];
        load8(lA + (size_t)r * KDIM + d0, av);
#pragma unroll
        for (int e = 0; e < 8; ++e) lor[e] += Bo[r] * av[e];
    }

    int4v ov4;
    bf16* ov = (bf16*)&ov4;
#pragma unroll
    for (int e = 0; e < 8; ++e) {
        float a = wv[e] + SCALING * lor[e];
        if (mk[e]) a += dv[e];
        ov[e] = __float2bfloat16(a);
    }
    *(int4v*)(Weff + base) = ov4;
}

// ---------------------------------------------------------------------------
// GEMM (bf16 inputs): out[m][n] = sum_k X[m][k]*Wt[n][k] + bias[n], bf16 out.
// 128x128 tile, BK=64, 2x2 waves, 4x4 mfma_f32_16x16x32_bf16 per wave.
// global_load_lds width=16; XOR swizzle on 16B chunks kills bank conflicts.
// ---------------------------------------------------------------------------
__global__ __launch_bounds__(256, 3) void gemm_bf16(
    const bf16* __restrict__ X, const bf16* __restrict__ Wt,
    const bf16* __restrict__ bias, bf16* __restrict__ out)
{
    if (g_isf32 != 0) return;
    __shared__ bf16 As[128 * 64];   // 16 KB
    __shared__ bf16 Bs[128 * 64];   // 16 KB

    const int tid  = threadIdx.x;
    const int lane = tid & 63;
    const int wave = tid >> 6;
    const int wm   = wave & 1;
    const int wn   = wave >> 1;
    const int quad = lane >> 4;
    const int l16  = lane & 15;

    const int bn = blockIdx.x * 128;
    const int bm = blockIdx.y * 128;
    const int cwave = tid & ~63;

    f32x4 acc[4][4];
#pragma unroll
    for (int i = 0; i < 4; ++i)
#pragma unroll
        for (int j = 0; j < 4; ++j)
            acc[i][j] = (f32x4){0.f, 0.f, 0.f, 0.f};

    for (int kt = 0; kt < KDIM / 64; ++kt) {
        const int k0 = kt * 64;
        if (kt) __syncthreads();
#pragma unroll
        for (int j = 0; j < 4; ++j) {
            const int c  = j * 256 + tid;
            const int m  = c >> 3;
            const int kc = (c & 7) ^ (m & 7);
            const int cb = j * 256 + cwave;
            __builtin_amdgcn_global_load_lds(
                (const AS1 void*)(X + (size_t)(bm + m) * KDIM + k0 + kc * 8),
                (AS3 void*)(As + cb * 8), 16, 0, 0);
            __builtin_amdgcn_global_load_lds(
                (const AS1 void*)(Wt + (size_t)(bn + m) * KDIM + k0 + kc * 8),
                (AS3 void*)(Bs + cb * 8), 16, 0, 0);
        }
        __syncthreads();

#pragma unroll
        for (int ks = 0; ks < 2; ++ks) {
            bf16x8 af[4], bfr[4];
#pragma unroll
            for (int i = 0; i < 4; ++i) {
                const int m   = wm * 64 + i * 16 + l16;
                const int kca = (ks * 4 + quad) ^ (m & 7);
                af[i] = *(const bf16x8*)(As + m * 64 + kca * 8);
                const int n   = wn * 64 + i * 16 + l16;
                const int kcb = (ks * 4 + quad) ^ (n & 7);
                bfr[i] = *(const bf16x8*)(Bs + n * 64 + kcb * 8);
            }
#pragma unroll
            for (int i = 0; i < 4; ++i)
#pragma unroll
                for (int j = 0; j < 4; ++j)
                    acc[i][j] = __builtin_amdgcn_mfma_f32_16x16x32_bf16(
                        af[i], bfr[j], acc[i][j], 0, 0, 0);
        }
    }

    float bv[4];
#pragma unroll
    for (int j = 0; j < 4; ++j)
        bv[j] = tofl(bias[bn + wn * 64 + j * 16 + l16]);

#pragma unroll
    for (int i = 0; i < 4; ++i) {
        const int mg = bm + wm * 64 + i * 16 + quad * 4;
#pragma unroll
        for (int j = 0; j < 4; ++j) {
            const int ng = bn + wn * 64 + j * 16 + l16;
#pragma unroll
            for (int r = 0; r < 4; ++r)
                out[(size_t)(mg + r) * NDIM + ng] =
                    __float2bfloat16(acc[i][j][r] + bv[j]);
        }
    }
}

// ---------------------------------------------------------------------------
// GEMM (fp32 X / fp32 out): stage X as f32 (32 KB), convert to bf16 at
// fragment read; Weff is bf16 already. 48 KB LDS total.
// ---------------------------------------------------------------------------
__global__ __launch_bounds__(256, 3) void gemm_f32(
    const float* __restrict__ X, const bf16* __restrict__ Wt,
    const float* __restrict__ bias, float* __restrict__ out)
{
    if (g_isf32 != 1) return;
    __shared__ float Asf[128 * 64];  // 32 KB, rows of 16 chunks (16B = 4 f32)
    __shared__ bf16  Bs[128 * 64];   // 16 KB, rows of 8 chunks

    const int tid  = threadIdx.x;
    const int lane = tid & 63;
    const int wave = tid >> 6;
    const int wm   = wave & 1;
    const int wn   = wave >> 1;
    const int quad = lane >> 4;
    const int l16  = lane & 15;

    const int bn = blockIdx.x * 128;
    const int bm = blockIdx.y * 128;
    const int cwave = tid & ~63;

    f32x4 acc[4][4];
#pragma unroll
    for (int i = 0; i < 4; ++i)
#pragma unroll
        for (int j = 0; j < 4; ++j)
            acc[i][j] = (f32x4){0.f, 0.f, 0.f, 0.f};

    for (int kt = 0; kt < KDIM / 64; ++kt) {
        const int k0 = kt * 64;
        if (kt) __syncthreads();

        // A: 128 rows x 64 f32 = 2048 16B-chunks, 8 per thread
#pragma unroll
        for (int j = 0; j < 8; ++j) {
            const int c  = j * 256 + tid;
            const int m  = c >> 4;
            const int kc = (c & 15) ^ (m & 15);     // 16B chunk = 4 floats
            const int cb = j * 256 + cwave;
            __builtin_amdgcn_global_load_lds(
                (const AS1 void*)(X + (size_t)(bm + m) * KDIM + k0 + kc * 4),
                (AS3 void*)(Asf + cb * 4), 16, 0, 0);
        }
        // B: 1024 chunks, 4 per thread (bf16, 8 elems per 16B chunk)
#pragma unroll
        for (int j = 0; j < 4; ++j) {
            const int c  = j * 256 + tid;
            const int m  = c >> 3;
            const int kc = (c & 7) ^ (m & 7);
            const int cb = j * 256 + cwave;
            __builtin_amdgcn_global_load_lds(
                (const AS1 void*)(Wt + (size_t)(bn + m) * KDIM + k0 + kc * 8),
                (AS3 void*)(Bs + cb * 8), 16, 0, 0);
        }
        __syncthreads();

#pragma unroll
        for (int ks = 0; ks < 2; ++ks) {
            bf16x8 af[4], bfr[4];
#pragma unroll
            for (int i = 0; i < 4; ++i) {
                const int m  = wm * 64 + i * 16 + l16;
                const int k2 = (ks * 4 + quad) * 2;          // two f32 chunks
                f32x4 lo = *(const f32x4*)(Asf + m * 64 + ((k2     ^ (m & 15)) * 4));
                f32x4 hi = *(const f32x4*)(Asf + m * 64 + (((k2+1) ^ (m & 15)) * 4));
                bf16 tmp[8];
#pragma unroll
                for (int e = 0; e < 4; ++e) {
                    tmp[e]     = __float2bfloat16(lo[e]);
                    tmp[e + 4] = __float2bfloat16(hi[e]);
                }
                af[i] = *(const bf16x8*)tmp;

                const int n   = wn * 64 + i * 16 + l16;
                const int kcb = (ks * 4 + quad) ^ (n & 7);
                bfr[i] = *(const bf16x8*)(Bs + n * 64 + kcb * 8);
            }
#pragma unroll
            for (int i = 0; i < 4; ++i)
#pragma unroll
                for (int j = 0; j < 4; ++j)
                    acc[i][j] = __builtin_amdgcn_mfma_f32_16x16x32_bf16(
                        af[i], bfr[j], acc[i][j], 0, 0, 0);
        }
    }

    float bv[4];
#pragma unroll
    for (int j = 0; j < 4; ++j)
        bv[j] = bias[bn + wn * 64 + j * 16 + l16];

#pragma unroll
    for (int i = 0; i < 4; ++i) {
        const int mg = bm + wm * 64 + i * 16 + quad * 4;
#pragma unroll
        for (int j = 0; j < 4; ++j) {
            const int ng = bn + wn * 64 + j * 16 + l16;
#pragma unroll
            for (int r = 0; r < 4; ++r)
                out[(size_t)(mg + r) * NDIM + ng] = acc[i][j][r] + bv[j];
        }
    }
}

// ---------------------------------------------------------------------------
extern "C" void kernel_launch(void* const* d_in, const int* in_sizes, int n_in,
                              void* d_out, int out_size, void* d_ws, size_t ws_size,
                              hipStream_t stream)
{
    bf16* Weff = (bf16*)d_ws;   // 32 MB scratch, rewritten every call

    detect_dtype<<<1, 256, 0, stream>>>((const unsigned short*)d_in[0]);

    // fp32 pipeline (reference dtypes) — runs iff g_isf32 == 1
    fold_weff<float><<<dim3((NDIM * KDIM / 8) / 256), 256, 0, stream>>>(
        (const float*)d_in[1], (const float*)d_in[3], (const float*)d_in[4],
        (const float*)d_in[5], (const int*)d_in[6], Weff, 1);
    gemm_f32<<<dim3(NDIM / 128, MDIM / 128), 256, 0, stream>>>(
        (const float*)d_in[0], Weff, (const float*)d_in[2], (float*)d_out);

    // bf16 pipeline (converted harness) — runs iff g_isf32 == 0
    fold_weff<bf16><<<dim3((NDIM * KDIM / 8) / 256), 256, 0, stream>>>(
        (const bf16*)d_in[1], (const bf16*)d_in[3], (const bf16*)d_in[4],
        (const bf16*)d_in[5], (const int*)d_in[6], Weff, 0);
    gemm_bf16<<<dim3(NDIM / 128, MDIM / 128), 256, 0, stream>>>(
        (const bf16*)d_in[0], Weff, (const bf16*)d_in[2], (bf16*)d_out);
}

// Round 3
// 647.370 us; speedup vs baseline: 1.1258x; 1.1258x over previous
//
#include <hip/hip_runtime.h>
#include <hip/hip_bf16.h>

typedef __hip_bfloat16 bf16;
typedef __attribute__((ext_vector_type(8))) short bf16x8;   // 8 bf16 = 4 VGPRs
typedef __attribute__((ext_vector_type(4))) float f32x4;
typedef __attribute__((ext_vector_type(4))) int int4v;

#define AS1 __attribute__((address_space(1)))
#define AS3 __attribute__((address_space(3)))

#define MDIM 8192   // B*S
#define NDIM 4096   // D_OUT
#define KDIM 4096   // D_IN
#define SCALING 2.0f

// ---------------------------------------------------------------------------
// Fold: Weff[o][d] = W + SCALING*(lora_B@lora_A) + (mask?delta:0)  -> bf16
// ~234 MB HBM traffic, memory-bound.
// ---------------------------------------------------------------------------
__global__ __launch_bounds__(256) void fold_weff(
    const float* __restrict__ W, const float* __restrict__ lA,
    const float* __restrict__ lB, const float* __restrict__ delta,
    const int* __restrict__ mask, bf16* __restrict__ Weff)
{
    int idx = blockIdx.x * 256 + threadIdx.x;   // 2,097,152 total
    int o   = idx >> 9;                          // 512 threads per row of 4096
    int d0  = (idx & 511) << 3;
    size_t base = (size_t)o * KDIM + d0;

    float Bo[16];
#pragma unroll
    for (int r = 0; r < 16; ++r) Bo[r] = lB[o * 16 + r];

    f32x4 wa = *(const f32x4*)(W + base);
    f32x4 wb = *(const f32x4*)(W + base + 4);
    f32x4 da = *(const f32x4*)(delta + base);
    f32x4 db = *(const f32x4*)(delta + base + 4);

    int mk[8];
    *(int4v*)(mk)     = *(const int4v*)(mask + base);
    *(int4v*)(mk + 4) = *(const int4v*)(mask + base + 4);

    float lor[8] = {0.f, 0.f, 0.f, 0.f, 0.f, 0.f, 0.f, 0.f};
#pragma unroll
    for (int r = 0; r < 16; ++r) {
        f32x4 aa = *(const f32x4*)(lA + (size_t)r * KDIM + d0);
        f32x4 ab = *(const f32x4*)(lA + (size_t)r * KDIM + d0 + 4);
#pragma unroll
        for (int e = 0; e < 4; ++e) {
            lor[e]     += Bo[r] * aa[e];
            lor[e + 4] += Bo[r] * ab[e];
        }
    }

    int4v ov4;
    bf16* ov = (bf16*)&ov4;
#pragma unroll
    for (int e = 0; e < 8; ++e) {
        float w = (e < 4) ? wa[e] : wb[e - 4];
        float d = (e < 4) ? da[e] : db[e - 4];
        float a = w + SCALING * lor[e];
        if (mk[e]) a += d;
        ov[e] = __float2bfloat16(a);
    }
    *(int4v*)(Weff + base) = ov4;
}

// ---------------------------------------------------------------------------
// Convert X fp32 -> bf16 (201 MB traffic, ~35 us)
// ---------------------------------------------------------------------------
__global__ __launch_bounds__(256) void convert_x(
    const float* __restrict__ X, bf16* __restrict__ Xb)
{
    size_t i = ((size_t)blockIdx.x * 256 + threadIdx.x) * 8;
    f32x4 a = *(const f32x4*)(X + i);
    f32x4 b = *(const f32x4*)(X + i + 4);
    int4v ov4;
    bf16* ov = (bf16*)&ov4;
#pragma unroll
    for (int e = 0; e < 4; ++e) {
        ov[e]     = __float2bfloat16(a[e]);
        ov[e + 4] = __float2bfloat16(b[e]);
    }
    *(int4v*)(Xb + i) = ov4;
}

// ---------------------------------------------------------------------------
// GEMM (bf16 x bf16 -> fp32): out[m][n] = sum_k Xb[m][k]*Wt[n][k] + bias[n]
// m97 structure: 128x128 tile, BK=64, 2x2 waves, 4x4 mfma_f32_16x16x32_bf16.
// global_load_lds width=16; XOR swizzle on 16B chunks -> 0 bank conflicts.
// LDS 32 KB -> 5 blocks/CU possible.
// ---------------------------------------------------------------------------
__global__ __launch_bounds__(256, 4) void gemm_bf16(
    const bf16* __restrict__ X, const bf16* __restrict__ Wt,
    const float* __restrict__ bias, float* __restrict__ out)
{
    __shared__ bf16 As[128 * 64];   // 16 KB
    __shared__ bf16 Bs[128 * 64];   // 16 KB

    const int tid  = threadIdx.x;
    const int lane = tid & 63;
    const int wave = tid >> 6;
    const int wm   = wave & 1;
    const int wn   = wave >> 1;
    const int quad = lane >> 4;
    const int l16  = lane & 15;

    const int bn = blockIdx.x * 128;
    const int bm = blockIdx.y * 128;
    const int cwave = tid & ~63;

    f32x4 acc[4][4];
#pragma unroll
    for (int i = 0; i < 4; ++i)
#pragma unroll
        for (int j = 0; j < 4; ++j)
            acc[i][j] = (f32x4){0.f, 0.f, 0.f, 0.f};

    for (int kt = 0; kt < KDIM / 64; ++kt) {
        const int k0 = kt * 64;
        if (kt) __syncthreads();
#pragma unroll
        for (int j = 0; j < 4; ++j) {
            const int c  = j * 256 + tid;
            const int m  = c >> 3;
            const int kc = (c & 7) ^ (m & 7);
            const int cb = j * 256 + cwave;
            __builtin_amdgcn_global_load_lds(
                (const AS1 void*)(X + (size_t)(bm + m) * KDIM + k0 + kc * 8),
                (AS3 void*)(As + cb * 8), 16, 0, 0);
            __builtin_amdgcn_global_load_lds(
                (const AS1 void*)(Wt + (size_t)(bn + m) * KDIM + k0 + kc * 8),
                (AS3 void*)(Bs + cb * 8), 16, 0, 0);
        }
        __syncthreads();

#pragma unroll
        for (int ks = 0; ks < 2; ++ks) {
            bf16x8 af[4], bfr[4];
#pragma unroll
            for (int i = 0; i < 4; ++i) {
                const int m   = wm * 64 + i * 16 + l16;
                const int kca = (ks * 4 + quad) ^ (m & 7);
                af[i] = *(const bf16x8*)(As + m * 64 + kca * 8);
                const int n   = wn * 64 + i * 16 + l16;
                const int kcb = (ks * 4 + quad) ^ (n & 7);
                bfr[i] = *(const bf16x8*)(Bs + n * 64 + kcb * 8);
            }
#pragma unroll
            for (int i = 0; i < 4; ++i)
#pragma unroll
                for (int j = 0; j < 4; ++j)
                    acc[i][j] = __builtin_amdgcn_mfma_f32_16x16x32_bf16(
                        af[i], bfr[j], acc[i][j], 0, 0, 0);
        }
    }

    // C/D layout: col = lane&15, row = quad*4 + reg
    float bv[4];
#pragma unroll
    for (int j = 0; j < 4; ++j)
        bv[j] = bias[bn + wn * 64 + j * 16 + l16];

#pragma unroll
    for (int i = 0; i < 4; ++i) {
        const int mg = bm + wm * 64 + i * 16 + quad * 4;
#pragma unroll
        for (int j = 0; j < 4; ++j) {
            const int ng = bn + wn * 64 + j * 16 + l16;
#pragma unroll
            for (int r = 0; r < 4; ++r)
                out[(size_t)(mg + r) * NDIM + ng] = acc[i][j][r] + bv[j];
        }
    }
}

// ---------------------------------------------------------------------------
// Fallback GEMM (fp32 X staged as f32 in LDS) — proven in round 2; used only
// if ws_size can't fit the bf16 copy of X.
// ---------------------------------------------------------------------------
__global__ __launch_bounds__(256, 3) void gemm_f32(
    const float* __restrict__ X, const bf16* __restrict__ Wt,
    const float* __restrict__ bias, float* __restrict__ out)
{
    __shared__ float Asf[128 * 64];  // 32 KB
    __shared__ bf16  Bs[128 * 64];   // 16 KB

    const int tid  = threadIdx.x;
    const int lane = tid & 63;
    const int wave = tid >> 6;
    const int wm   = wave & 1;
    const int wn   = wave >> 1;
    const int quad = lane >> 4;
    const int l16  = lane & 15;

    const int bn = blockIdx.x * 128;
    const int bm = blockIdx.y * 128;
    const int cwave = tid & ~63;

    f32x4 acc[4][4];
#pragma unroll
    for (int i = 0; i < 4; ++i)
#pragma unroll
        for (int j = 0; j < 4; ++j)
            acc[i][j] = (f32x4){0.f, 0.f, 0.f, 0.f};

    for (int kt = 0; kt < KDIM / 64; ++kt) {
        const int k0 = kt * 64;
        if (kt) __syncthreads();
#pragma unroll
        for (int j = 0; j < 8; ++j) {
            const int c  = j * 256 + tid;
            const int m  = c >> 4;
            const int kc = (c & 15) ^ (m & 15);
            const int cb = j * 256 + cwave;
            __builtin_amdgcn_global_load_lds(
                (const AS1 void*)(X + (size_t)(bm + m) * KDIM + k0 + kc * 4),
                (AS3 void*)(Asf + cb * 4), 16, 0, 0);
        }
#pragma unroll
        for (int j = 0; j < 4; ++j) {
            const int c  = j * 256 + tid;
            const int m  = c >> 3;
            const int kc = (c & 7) ^ (m & 7);
            const int cb = j * 256 + cwave;
            __builtin_amdgcn_global_load_lds(
                (const AS1 void*)(Wt + (size_t)(bn + m) * KDIM + k0 + kc * 8),
                (AS3 void*)(Bs + cb * 8), 16, 0, 0);
        }
        __syncthreads();

#pragma unroll
        for (int ks = 0; ks < 2; ++ks) {
            bf16x8 af[4], bfr[4];
#pragma unroll
            for (int i = 0; i < 4; ++i) {
                const int m  = wm * 64 + i * 16 + l16;
                const int k2 = (ks * 4 + quad) * 2;
                f32x4 lo = *(const f32x4*)(Asf + m * 64 + ((k2     ^ (m & 15)) * 4));
                f32x4 hi = *(const f32x4*)(Asf + m * 64 + (((k2+1) ^ (m & 15)) * 4));
                bf16 tmp[8];
#pragma unroll
                for (int e = 0; e < 4; ++e) {
                    tmp[e]     = __float2bfloat16(lo[e]);
                    tmp[e + 4] = __float2bfloat16(hi[e]);
                }
                af[i] = *(const bf16x8*)tmp;

                const int n   = wn * 64 + i * 16 + l16;
                const int kcb = (ks * 4 + quad) ^ (n & 7);
                bfr[i] = *(const bf16x8*)(Bs + n * 64 + kcb * 8);
            }
#pragma unroll
            for (int i = 0; i < 4; ++i)
#pragma unroll
                for (int j = 0; j < 4; ++j)
                    acc[i][j] = __builtin_amdgcn_mfma_f32_16x16x32_bf16(
                        af[i], bfr[j], acc[i][j], 0, 0, 0);
        }
    }

    float bv[4];
#pragma unroll
    for (int j = 0; j < 4; ++j)
        bv[j] = bias[bn + wn * 64 + j * 16 + l16];

#pragma unroll
    for (int i = 0; i < 4; ++i) {
        const int mg = bm + wm * 64 + i * 16 + quad * 4;
#pragma unroll
        for (int j = 0; j < 4; ++j) {
            const int ng = bn + wn * 64 + j * 16 + l16;
#pragma unroll
            for (int r = 0; r < 4; ++r)
                out[(size_t)(mg + r) * NDIM + ng] = acc[i][j][r] + bv[j];
        }
    }
}

// ---------------------------------------------------------------------------
extern "C" void kernel_launch(void* const* d_in, const int* in_sizes, int n_in,
                              void* d_out, int out_size, void* d_ws, size_t ws_size,
                              hipStream_t stream)
{
    const float* x     = (const float*)d_in[0];
    const float* W     = (const float*)d_in[1];
    const float* b     = (const float*)d_in[2];
    const float* lA    = (const float*)d_in[3];
    const float* lB    = (const float*)d_in[4];
    const float* delta = (const float*)d_in[5];
    const int*   mask  = (const int*)d_in[6];
    float* out = (float*)d_out;

    bf16* Weff = (bf16*)d_ws;                               // 33.5 MB
    bf16* Xb   = (bf16*)((char*)d_ws + (size_t)NDIM * KDIM * 2);  // 67 MB

    const size_t need = (size_t)NDIM * KDIM * 2 + (size_t)MDIM * KDIM * 2;

    fold_weff<<<dim3((NDIM * KDIM / 8) / 256), 256, 0, stream>>>(
        W, lA, lB, delta, mask, Weff);

    if (ws_size >= need) {
        convert_x<<<dim3((MDIM * KDIM / 8) / 256), 256, 0, stream>>>(x, Xb);
        gemm_bf16<<<dim3(NDIM / 128, MDIM / 128), 256, 0, stream>>>(
            Xb, Weff, b, out);
    } else {
        gemm_f32<<<dim3(NDIM / 128, MDIM / 128), 256, 0, stream>>>(
            x, Weff, b, out);
    }
}